// Round 13
// baseline (171.598 us; speedup 1.0000x reference)
//
#include <hip/hip_runtime.h>
#include <hip/hip_bf16.h>

#define HD 768
#define SQ 256
#define NB 4
#define RR 7

typedef short bf16x8 __attribute__((ext_vector_type(8)));
typedef float f32x4  __attribute__((ext_vector_type(4)));

__device__ __forceinline__ float fast_tanh(float x) {
  // tanh(x) = 1 - 2/(e^{2x}+1); stable for large |x|
  float e = __expf(2.0f * x);
  return 1.0f - 2.0f / (e + 1.0f);
}

__device__ __forceinline__ float pair_tanh(float a, float b) {
  // tanh(u+v) = (a+b)/(1+ab) with a=tanh u, b=tanh v (exact identity)
  return (a + b) * __builtin_amdgcn_rcpf(fmaf(a, b, 1.0f));
}

__device__ __forceinline__ short f2bf(float x) {
  return (short)__builtin_bit_cast(unsigned short, __float2bfloat16(x));
}

__device__ __forceinline__ void gl_lds16(const void* g, void* l) {
  // async 16B/lane global->LDS; LDS dest = wave-uniform base + lane*16
  __builtin_amdgcn_global_load_lds(
      (const __attribute__((address_space(1))) void*)g,
      (__attribute__((address_space(3))) void*)l, 16, 0, 0);
}

// ------- convert: f32 -> bf16 for X, Wsrc, Wtgt; Wout padded to 16 rows -------
__global__ __launch_bounds__(256) void cvt_kernel(
    const float* __restrict__ X, const float* __restrict__ Ws,
    const float* __restrict__ Wt, const float* __restrict__ Wo,
    short* __restrict__ Xb, short* __restrict__ Wsb,
    short* __restrict__ Wtb, short* __restrict__ Wob)
{
  const int NX = NB * SQ * HD / 8;   // 98304 octets
  const int NW = HD * HD / 8;        // 73728 octets
  const int NO = 16 * HD / 8;        // 1536 octets (padded rows)
  int i = blockIdx.x * 256 + threadIdx.x;
  const float* src; short* dst;
  if (i < NX)               { src = X;  dst = Xb; }
  else if (i < NX + NW)     { src = Ws; dst = Wsb; i -= NX; }
  else if (i < NX + 2 * NW) { src = Wt; dst = Wtb; i -= NX + NW; }
  else if (i < NX + 2 * NW + NO) {
    i -= NX + 2 * NW;
    int row = i / (HD / 8);
    bf16x8 r = {};
    if (row < RR) {
      float4 a = *(const float4*)(Wo + (size_t)i * 8);
      float4 b = *(const float4*)(Wo + (size_t)i * 8 + 4);
      r[0] = f2bf(a.x); r[1] = f2bf(a.y); r[2] = f2bf(a.z); r[3] = f2bf(a.w);
      r[4] = f2bf(b.x); r[5] = f2bf(b.y); r[6] = f2bf(b.z); r[7] = f2bf(b.w);
    }
    *(bf16x8*)(Wob + (size_t)i * 8) = r;
    return;
  } else return;
  float4 a = *(const float4*)(src + (size_t)i * 8);
  float4 b = *(const float4*)(src + (size_t)i * 8 + 4);
  bf16x8 r;
  r[0] = f2bf(a.x); r[1] = f2bf(a.y); r[2] = f2bf(a.z); r[3] = f2bf(a.w);
  r[4] = f2bf(b.x); r[5] = f2bf(b.y); r[6] = f2bf(b.z); r[7] = f2bf(b.w);
  *(bf16x8*)(dst + (size_t)i * 8) = r;
}

// small fallback converter: Wout only (padded to 16 rows)
__global__ __launch_bounds__(256) void cvt_wout(
    const float* __restrict__ Wo, short* __restrict__ Wob)
{
  const int NO = 16 * HD / 8;
  int i = blockIdx.x * 256 + threadIdx.x;
  if (i >= NO) return;
  int row = i / (HD / 8);
  bf16x8 r = {};
  if (row < RR) {
    float4 a = *(const float4*)(Wo + (size_t)i * 8);
    float4 b = *(const float4*)(Wo + (size_t)i * 8 + 4);
    r[0] = f2bf(a.x); r[1] = f2bf(a.y); r[2] = f2bf(a.z); r[3] = f2bf(a.w);
    r[4] = f2bf(b.x); r[5] = f2bf(b.y); r[6] = f2bf(b.z); r[7] = f2bf(b.w);
  }
  *(bf16x8*)(Wob + (size_t)i * 8) = r;
}

// -------- Stage 1: ta/tb = tanh(Xb @ Wb^T + bias); BM=32 tile, 768 blocks --------
__global__ __launch_bounds__(256) void stage1_lds(
    const short* __restrict__ Xb,
    const short* __restrict__ Wsb, const float* __restrict__ bsrc,
    const short* __restrict__ Wtb, const float* __restrict__ btgt,
    float* __restrict__ ta, float* __restrict__ tb)
{
  constexpr int BK = 64, BM = 32, BN = 64;
  const short* W  = blockIdx.z ? Wtb : Wsb;
  const float* bv = blockIdx.z ? btgt : bsrc;
  float* outp     = blockIdx.z ? tb : ta;
  const int row0 = blockIdx.x * BM, col0 = blockIdx.y * BN;

  // double-buffered; content granule(r,g) = global (r, g^(r&7))
  __shared__ short As[2][BM * BK];   // 4 KB per buf
  __shared__ short Bs[2][BN * BK];   // 8 KB per buf

  const int tid = threadIdx.x, wave = tid >> 6, lane = tid & 63;
  const int ln = lane & 15, lg = lane >> 4;
  const int wm = (wave >> 1) * 16, wn = (wave & 1) * 32;

  f32x4 acc[2] = {};

  // A staging: 256 granules (32 rows x 8/row), one per thread
  const int ra = tid >> 3, ga = tid & 7;
  const size_t xoff = (size_t)(row0 + ra) * HD + ((ga ^ (ra & 7)) * 8);
  // B staging: 512 granules (64 rows x 8/row), threads t and t+256
  const int rb0 = tid >> 3, gb0 = tid & 7;
  const int rb1 = (tid + 256) >> 3, gb1 = tid & 7;
  const size_t wof0 = (size_t)(col0 + rb0) * HD + ((gb0 ^ (rb0 & 7)) * 8);
  const size_t wof1 = (size_t)(col0 + rb1) * HD + ((gb1 ^ (rb1 & 7)) * 8);
  short* const laA  = (short*)As + (size_t)(wave * 64) * 8;
  short* const laB0 = (short*)Bs + (size_t)(wave * 64) * 8;
  short* const laB1 = (short*)Bs + (size_t)(256 + wave * 64) * 8;
  constexpr int BUFA = BM * BK, BUFB = BN * BK;

  // prologue: stage tile 0 into buf 0
  gl_lds16(Xb + xoff, laA);
  gl_lds16(W + wof0, laB0);
  gl_lds16(W + wof1, laB1);

  int cur = 0;
  for (int k0 = 0; k0 < HD; k0 += BK) {
    __syncthreads();   // drains vmcnt: buf[cur] ready; prev reads of buf[cur^1] done
    if (k0 + BK < HD) {  // issue next tile into buf[cur^1]; flies under compute
      gl_lds16(Xb + xoff + k0 + BK, laA + (cur ^ 1) * BUFA);
      gl_lds16(W + wof0 + k0 + BK, laB0 + (cur ^ 1) * BUFB);
      gl_lds16(W + wof1 + k0 + BK, laB1 + (cur ^ 1) * BUFB);
    }
    const short* Ac = (const short*)As + cur * BUFA;
    const short* Bc = (const short*)Bs + cur * BUFB;

    #pragma unroll
    for (int kkb = 0; kkb < 2; ++kkb) {
      const int q = kkb * 4 + lg;
      const int ar = wm + ln;
      bf16x8 af = *(const bf16x8*)&Ac[ar * BK + ((q ^ (ar & 7)) * 8)];
      bf16x8 bw[2];
      #pragma unroll
      for (int i = 0; i < 2; ++i) {
        int br = wn + i * 16 + ln;
        bw[i] = *(const bf16x8*)&Bc[br * BK + ((q ^ (br & 7)) * 8)];
      }
      #pragma unroll
      for (int i = 0; i < 2; ++i)
        acc[i] = __builtin_amdgcn_mfma_f32_16x16x32_bf16(af, bw[i], acc[i], 0, 0, 0);
    }
    cur ^= 1;
  }

  #pragma unroll
  for (int j = 0; j < 2; ++j) {
    int n = col0 + wn + j * 16 + ln;
    float bb = bv[n];
    #pragma unroll
    for (int r = 0; r < 4; ++r) {
      int m = row0 + wm + lg * 4 + r;
      outp[(size_t)m * HD + n] = fast_tanh(acc[j][r] + bb);
    }
  }
}

// -------- Stage 1 fallback (in-kernel convert; used if ws too small) --------
__global__ __launch_bounds__(256) void stage1_mfma(
    const float* __restrict__ X,
    const float* __restrict__ Wsrc, const float* __restrict__ bsrc,
    const float* __restrict__ Wtgt, const float* __restrict__ btgt,
    float* __restrict__ ta, float* __restrict__ tb)
{
  constexpr int BK = 64;
  const float* W  = blockIdx.z ? Wtgt : Wsrc;
  const float* bv = blockIdx.z ? btgt : bsrc;
  float* outp     = blockIdx.z ? tb : ta;
  const int row0 = blockIdx.x * 64, col0 = blockIdx.y * 64;

  __shared__ short As[64 * BK];
  __shared__ short Bs[64 * BK];

  const int tid  = threadIdx.x;
  const int wave = tid >> 6, lane = tid & 63;
  const int wm = (wave >> 1) * 32, wn = (wave & 1) * 32;
  f32x4 acc[2][2] = {};
  const int sr = tid >> 2, sq = tid & 3;

  for (int k0 = 0; k0 < HD; k0 += BK) {
    const float* xa = X + (size_t)(row0 + sr) * HD + k0 + sq * 16;
    const float* xw = W + (size_t)(col0 + sr) * HD + k0 + sq * 16;
    float4 a0 = *(const float4*)(xa + 0), a1 = *(const float4*)(xa + 4);
    float4 a2 = *(const float4*)(xa + 8), a3 = *(const float4*)(xa + 12);
    float4 w0 = *(const float4*)(xw + 0), w1 = *(const float4*)(xw + 4);
    float4 w2 = *(const float4*)(xw + 8), w3 = *(const float4*)(xw + 12);
    __syncthreads();
    bf16x8 p;
    p[0]=f2bf(a0.x);p[1]=f2bf(a0.y);p[2]=f2bf(a0.z);p[3]=f2bf(a0.w);
    p[4]=f2bf(a1.x);p[5]=f2bf(a1.y);p[6]=f2bf(a1.z);p[7]=f2bf(a1.w);
    *(bf16x8*)&As[sr * BK + (((sq * 2 + 0) ^ (sr & 7)) * 8)] = p;
    p[0]=f2bf(a2.x);p[1]=f2bf(a2.y);p[2]=f2bf(a2.z);p[3]=f2bf(a2.w);
    p[4]=f2bf(a3.x);p[5]=f2bf(a3.y);p[6]=f2bf(a3.z);p[7]=f2bf(a3.w);
    *(bf16x8*)&As[sr * BK + (((sq * 2 + 1) ^ (sr & 7)) * 8)] = p;
    p[0]=f2bf(w0.x);p[1]=f2bf(w0.y);p[2]=f2bf(w0.z);p[3]=f2bf(w0.w);
    p[4]=f2bf(w1.x);p[5]=f2bf(w1.y);p[6]=f2bf(w1.z);p[7]=f2bf(w1.w);
    *(bf16x8*)&Bs[sr * BK + (((sq * 2 + 0) ^ (sr & 7)) * 8)] = p;
    p[0]=f2bf(w2.x);p[1]=f2bf(w2.y);p[2]=f2bf(w2.z);p[3]=f2bf(w2.w);
    p[4]=f2bf(w3.x);p[5]=f2bf(w3.y);p[6]=f2bf(w3.z);p[7]=f2bf(w3.w);
    *(bf16x8*)&Bs[sr * BK + (((sq * 2 + 1) ^ (sr & 7)) * 8)] = p;
    __syncthreads();

    #pragma unroll
    for (int kkb = 0; kkb < 2; ++kkb) {
      bf16x8 af[2], bw[2];
      const int q = kkb * 4 + (lane >> 4);
      #pragma unroll
      for (int i = 0; i < 2; ++i) {
        int ar = wm + i * 16 + (lane & 15);
        af[i] = *(const bf16x8*)&As[ar * BK + ((q ^ (ar & 7)) * 8)];
        int br = wn + i * 16 + (lane & 15);
        bw[i] = *(const bf16x8*)&Bs[br * BK + ((q ^ (br & 7)) * 8)];
      }
      #pragma unroll
      for (int i = 0; i < 2; ++i)
        #pragma unroll
        for (int j = 0; j < 2; ++j)
          acc[i][j] = __builtin_amdgcn_mfma_f32_16x16x32_bf16(af[i], bw[j], acc[i][j], 0, 0, 0);
    }
  }

  #pragma unroll
  for (int j = 0; j < 2; ++j) {
    int n = col0 + wn + j * 16 + (lane & 15);
    float bb = bv[n];
    #pragma unroll
    for (int i = 0; i < 2; ++i)
      #pragma unroll
      for (int r = 0; r < 4; ++r) {
        int m = row0 + wm + i * 16 + (lane >> 4) * 4 + r;
        outp[(size_t)m * HD + n] = fast_tanh(acc[i][j][r] + bb);
      }
  }
}

// ---- Stage 2: out[b,s,t,r] via MFMA; NO LDS, no barriers.
//      8s x 16t tile, wave owns 2 s-rows; all operands read direct from
//      global (L1/L2-resident): ta slice is 16-lane-broadcast, tb/Wout are
//      16B granules. Eliminates the ds_read pipe bottleneck (~12cyc/b128). ----
__global__ __launch_bounds__(256, 6) void stage2_mfma(
    const float* __restrict__ ta, const float* __restrict__ tb,
    const short* __restrict__ Wob, float* __restrict__ out)
{
  const int b  = blockIdx.z;
  const int s0 = blockIdx.y * 8, t0 = blockIdx.x * 16;

  const int tid = threadIdx.x, wave = tid >> 6, lane = tid & 63;
  const int lg = lane >> 4;       // k sub-group (0..3) / output t-quad
  const int ln = lane & 15;       // A-row t / B-col r

  f32x4 acc[2] = {};              // one per owned s-row, full-K accumulate

  // per-lane base pointers (kk = m*32 + lg*8 walks with m)
  const float* a0p = ta + ((size_t)b * SQ + s0 + wave * 2 + 0) * HD + lg * 8;
  const float* a1p = ta + ((size_t)b * SQ + s0 + wave * 2 + 1) * HD + lg * 8;
  const float* bp  = tb + ((size_t)b * SQ + t0 + ln) * HD + lg * 8;
  const short* wp  = Wob + (size_t)ln * HD + lg * 8;

  #pragma unroll 4
  for (int m = 0; m < HD / 32; ++m) {
    const int kk = m * 32;
    // B fragment from padded bf16 Wout (rows 7..15 zeros); L1-resident
    bf16x8 bfr = *(const bf16x8*)(wp + kk);
    // tb values for this lane's t row
    float4 q0 = *(const float4*)(bp + kk);
    float4 q1 = *(const float4*)(bp + kk + 4);
    float bvv[8] = {q0.x,q0.y,q0.z,q0.w,q1.x,q1.y,q1.z,q1.w};

    #pragma unroll
    for (int si = 0; si < 2; ++si) {
      const float* ap = si ? a1p : a0p;     // broadcast across 16-lane group
      float4 a0 = *(const float4*)(ap + kk);
      float4 a1 = *(const float4*)(ap + kk + 4);
      float av[8] = {a0.x,a0.y,a0.z,a0.w,a1.x,a1.y,a1.z,a1.w};
      bf16x8 pa;
      #pragma unroll
      for (int j = 0; j < 8; ++j)
        pa[j] = f2bf(pair_tanh(av[j], bvv[j]));
      acc[si] = __builtin_amdgcn_mfma_f32_16x16x32_bf16(pa, bfr, acc[si], 0, 0, 0);
    }
  }

  // D layout: row(M=t) = lg*4+reg, col(N=r) = ln
  if (ln < RR) {
    #pragma unroll
    for (int si = 0; si < 2; ++si) {
      int s = s0 + wave * 2 + si;
      float* op = out + (((size_t)b * SQ + s) * SQ + t0 + lg * 4) * RR + ln;
      op[0]      = acc[si][0];
      op[RR]     = acc[si][1];
      op[2 * RR] = acc[si][2];
      op[3 * RR] = acc[si][3];
    }
  }
}

extern "C" void kernel_launch(void* const* d_in, const int* in_sizes, int n_in,
                              void* d_out, int out_size, void* d_ws, size_t ws_size,
                              hipStream_t stream) {
  (void)in_sizes; (void)n_in; (void)out_size;
  const float* X    = (const float*)d_in[0];
  const float* Wsrc = (const float*)d_in[1];
  const float* bsrc = (const float*)d_in[2];
  const float* Wtgt = (const float*)d_in[3];
  const float* btgt = (const float*)d_in[4];
  const float* Wout = (const float*)d_in[5];
  float* out = (float*)d_out;

  float* taF = (float*)d_ws;                       // [1024,768] f32
  float* tbF = taF + (size_t)NB * SQ * HD;         // [1024,768] f32
  const size_t base = (size_t)2 * NB * SQ * HD * sizeof(float);
  short* Xb  = (short*)((char*)d_ws + base);
  short* Wsb = Xb + (size_t)NB * SQ * HD;
  short* Wtb = Wsb + (size_t)HD * HD;
  short* Wob = Wtb + (size_t)HD * HD;
  const size_t need = base +
      ((size_t)NB * SQ * HD + 2 * (size_t)HD * HD + (size_t)16 * HD) * sizeof(short);

  const short* WobUse;
  if (ws_size >= need) {
    const int total_oct = NB*SQ*HD/8 + 2*(HD*HD/8) + 16*HD/8;
    cvt_kernel<<<(total_oct + 255) / 256, 256, 0, stream>>>(
        X, Wsrc, Wtgt, Wout, Xb, Wsb, Wtb, Wob);
    stage1_lds<<<dim3(32, 12, 2), 256, 0, stream>>>(Xb, Wsb, bsrc, Wtb, btgt, taF, tbF);
    WobUse = Wob;
  } else {
    short* WobF = (short*)((char*)d_ws + base);   // only padded Wout bf16 after ta/tb
    cvt_wout<<<6, 256, 0, stream>>>(Wout, WobF);
    stage1_mfma<<<dim3(16, 12, 2), 256, 0, stream>>>(X, Wsrc, bsrc, Wtgt, btgt, taF, tbF);
    WobUse = WobF;
  }
  stage2_mfma<<<dim3(SQ / 16, SQ / 8, NB), 256, 0, stream>>>(taF, tbF, WobUse, out);
}

// Round 15
// 113.893 us; speedup vs baseline: 1.5067x; 1.5067x over previous
//
#include <hip/hip_runtime.h>
#include <hip/hip_bf16.h>

#define HD 768
#define SQ 256
#define NB 4
#define RR 7

typedef short bf16x8 __attribute__((ext_vector_type(8)));
typedef float f32x4  __attribute__((ext_vector_type(4)));
typedef float f32x2  __attribute__((ext_vector_type(2)));

__device__ __forceinline__ float fast_tanh(float x) {
  float e = __expf(2.0f * x);
  return 1.0f - 2.0f / (e + 1.0f);
}

__device__ __forceinline__ short f2bf(float x) {
  return (short)__builtin_bit_cast(unsigned short, __float2bfloat16(x));
}

__device__ __forceinline__ void gl_lds16(const void* g, void* l) {
  __builtin_amdgcn_global_load_lds(
      (const __attribute__((address_space(1))) void*)g,
      (__attribute__((address_space(3))) void*)l, 16, 0, 0);
}

// ------- convert: f32 -> bf16 for X, Wsrc, Wtgt; Wout padded to 16 rows -------
__global__ __launch_bounds__(256) void cvt_kernel(
    const float* __restrict__ X, const float* __restrict__ Ws,
    const float* __restrict__ Wt, const float* __restrict__ Wo,
    short* __restrict__ Xb, short* __restrict__ Wsb,
    short* __restrict__ Wtb, short* __restrict__ Wob)
{
  const int NX = NB * SQ * HD / 8;
  const int NW = HD * HD / 8;
  const int NO = 16 * HD / 8;
  int i = blockIdx.x * 256 + threadIdx.x;
  const float* src; short* dst;
  if (i < NX)               { src = X;  dst = Xb; }
  else if (i < NX + NW)     { src = Ws; dst = Wsb; i -= NX; }
  else if (i < NX + 2 * NW) { src = Wt; dst = Wtb; i -= NX + NW; }
  else if (i < NX + 2 * NW + NO) {
    i -= NX + 2 * NW;
    int row = i / (HD / 8);
    bf16x8 r = {};
    if (row < RR) {
      float4 a = *(const float4*)(Wo + (size_t)i * 8);
      float4 b = *(const float4*)(Wo + (size_t)i * 8 + 4);
      r[0] = f2bf(a.x); r[1] = f2bf(a.y); r[2] = f2bf(a.z); r[3] = f2bf(a.w);
      r[4] = f2bf(b.x); r[5] = f2bf(b.y); r[6] = f2bf(b.z); r[7] = f2bf(b.w);
    }
    *(bf16x8*)(Wob + (size_t)i * 8) = r;
    return;
  } else return;
  float4 a = *(const float4*)(src + (size_t)i * 8);
  float4 b = *(const float4*)(src + (size_t)i * 8 + 4);
  bf16x8 r;
  r[0] = f2bf(a.x); r[1] = f2bf(a.y); r[2] = f2bf(a.z); r[3] = f2bf(a.w);
  r[4] = f2bf(b.x); r[5] = f2bf(b.y); r[6] = f2bf(b.z); r[7] = f2bf(b.w);
  *(bf16x8*)(dst + (size_t)i * 8) = r;
}

// small fallback converter: Wout only (padded to 16 rows)
__global__ __launch_bounds__(256) void cvt_wout(
    const float* __restrict__ Wo, short* __restrict__ Wob)
{
  const int NO = 16 * HD / 8;
  int i = blockIdx.x * 256 + threadIdx.x;
  if (i >= NO) return;
  int row = i / (HD / 8);
  bf16x8 r = {};
  if (row < RR) {
    float4 a = *(const float4*)(Wo + (size_t)i * 8);
    float4 b = *(const float4*)(Wo + (size_t)i * 8 + 4);
    r[0] = f2bf(a.x); r[1] = f2bf(a.y); r[2] = f2bf(a.z); r[3] = f2bf(a.w);
    r[4] = f2bf(b.x); r[5] = f2bf(b.y); r[6] = f2bf(b.z); r[7] = f2bf(b.w);
  }
  *(bf16x8*)(Wob + (size_t)i * 8) = r;
}

// -------- Stage 1: ta/tb = tanh(Xb @ Wb^T + bias); BM=32 tile, 768 blocks --------
__global__ __launch_bounds__(256) void stage1_lds(
    const short* __restrict__ Xb,
    const short* __restrict__ Wsb, const float* __restrict__ bsrc,
    const short* __restrict__ Wtb, const float* __restrict__ btgt,
    float* __restrict__ ta, float* __restrict__ tb)
{
  constexpr int BK = 64, BM = 32, BN = 64;
  const short* W  = blockIdx.z ? Wtb : Wsb;
  const float* bv = blockIdx.z ? btgt : bsrc;
  float* outp     = blockIdx.z ? tb : ta;
  const int row0 = blockIdx.x * BM, col0 = blockIdx.y * BN;

  __shared__ short As[2][BM * BK];
  __shared__ short Bs[2][BN * BK];

  const int tid = threadIdx.x, wave = tid >> 6, lane = tid & 63;
  const int ln = lane & 15, lg = lane >> 4;
  const int wm = (wave >> 1) * 16, wn = (wave & 1) * 32;

  f32x4 acc[2] = {};

  const int ra = tid >> 3, ga = tid & 7;
  const size_t xoff = (size_t)(row0 + ra) * HD + ((ga ^ (ra & 7)) * 8);
  const int rb0 = tid >> 3, gb0 = tid & 7;
  const int rb1 = (tid + 256) >> 3, gb1 = tid & 7;
  const size_t wof0 = (size_t)(col0 + rb0) * HD + ((gb0 ^ (rb0 & 7)) * 8);
  const size_t wof1 = (size_t)(col0 + rb1) * HD + ((gb1 ^ (rb1 & 7)) * 8);
  short* const laA  = (short*)As + (size_t)(wave * 64) * 8;
  short* const laB0 = (short*)Bs + (size_t)(wave * 64) * 8;
  short* const laB1 = (short*)Bs + (size_t)(256 + wave * 64) * 8;
  constexpr int BUFA = BM * BK, BUFB = BN * BK;

  gl_lds16(Xb + xoff, laA);
  gl_lds16(W + wof0, laB0);
  gl_lds16(W + wof1, laB1);

  int cur = 0;
  for (int k0 = 0; k0 < HD; k0 += BK) {
    __syncthreads();
    if (k0 + BK < HD) {
      gl_lds16(Xb + xoff + k0 + BK, laA + (cur ^ 1) * BUFA);
      gl_lds16(W + wof0 + k0 + BK, laB0 + (cur ^ 1) * BUFB);
      gl_lds16(W + wof1 + k0 + BK, laB1 + (cur ^ 1) * BUFB);
    }
    const short* Ac = (const short*)As + cur * BUFA;
    const short* Bc = (const short*)Bs + cur * BUFB;

    #pragma unroll
    for (int kkb = 0; kkb < 2; ++kkb) {
      const int q = kkb * 4 + lg;
      const int ar = wm + ln;
      bf16x8 af = *(const bf16x8*)&Ac[ar * BK + ((q ^ (ar & 7)) * 8)];
      bf16x8 bw[2];
      #pragma unroll
      for (int i = 0; i < 2; ++i) {
        int br = wn + i * 16 + ln;
        bw[i] = *(const bf16x8*)&Bc[br * BK + ((q ^ (br & 7)) * 8)];
      }
      #pragma unroll
      for (int i = 0; i < 2; ++i)
        acc[i] = __builtin_amdgcn_mfma_f32_16x16x32_bf16(af, bw[i], acc[i], 0, 0, 0);
    }
    cur ^= 1;
  }

  #pragma unroll
  for (int j = 0; j < 2; ++j) {
    int n = col0 + wn + j * 16 + ln;
    float bb = bv[n];
    #pragma unroll
    for (int r = 0; r < 4; ++r) {
      int m = row0 + wm + lg * 4 + r;
      outp[(size_t)m * HD + n] = fast_tanh(acc[j][r] + bb);
    }
  }
}

// -------- Stage 1 fallback (in-kernel convert; used if ws too small) --------
__global__ __launch_bounds__(256) void stage1_mfma(
    const float* __restrict__ X,
    const float* __restrict__ Wsrc, const float* __restrict__ bsrc,
    const float* __restrict__ Wtgt, const float* __restrict__ btgt,
    float* __restrict__ ta, float* __restrict__ tb)
{
  constexpr int BK = 64;
  const float* W  = blockIdx.z ? Wtgt : Wsrc;
  const float* bv = blockIdx.z ? btgt : bsrc;
  float* outp     = blockIdx.z ? tb : ta;
  const int row0 = blockIdx.x * 64, col0 = blockIdx.y * 64;

  __shared__ short As[64 * BK];
  __shared__ short Bs[64 * BK];

  const int tid  = threadIdx.x;
  const int wave = tid >> 6, lane = tid & 63;
  const int wm = (wave >> 1) * 32, wn = (wave & 1) * 32;
  f32x4 acc[2][2] = {};
  const int sr = tid >> 2, sq = tid & 3;

  for (int k0 = 0; k0 < HD; k0 += BK) {
    const float* xa = X + (size_t)(row0 + sr) * HD + k0 + sq * 16;
    const float* xw = W + (size_t)(col0 + sr) * HD + k0 + sq * 16;
    float4 a0 = *(const float4*)(xa + 0), a1 = *(const float4*)(xa + 4);
    float4 a2 = *(const float4*)(xa + 8), a3 = *(const float4*)(xa + 12);
    float4 w0 = *(const float4*)(xw + 0), w1 = *(const float4*)(xw + 4);
    float4 w2 = *(const float4*)(xw + 8), w3 = *(const float4*)(xw + 12);
    __syncthreads();
    bf16x8 p;
    p[0]=f2bf(a0.x);p[1]=f2bf(a0.y);p[2]=f2bf(a0.z);p[3]=f2bf(a0.w);
    p[4]=f2bf(a1.x);p[5]=f2bf(a1.y);p[6]=f2bf(a1.z);p[7]=f2bf(a1.w);
    *(bf16x8*)&As[sr * BK + (((sq * 2 + 0) ^ (sr & 7)) * 8)] = p;
    p[0]=f2bf(a2.x);p[1]=f2bf(a2.y);p[2]=f2bf(a2.z);p[3]=f2bf(a2.w);
    p[4]=f2bf(a3.x);p[5]=f2bf(a3.y);p[6]=f2bf(a3.z);p[7]=f2bf(a3.w);
    *(bf16x8*)&As[sr * BK + (((sq * 2 + 1) ^ (sr & 7)) * 8)] = p;
    p[0]=f2bf(w0.x);p[1]=f2bf(w0.y);p[2]=f2bf(w0.z);p[3]=f2bf(w0.w);
    p[4]=f2bf(w1.x);p[5]=f2bf(w1.y);p[6]=f2bf(w1.z);p[7]=f2bf(w1.w);
    *(bf16x8*)&Bs[sr * BK + (((sq * 2 + 0) ^ (sr & 7)) * 8)] = p;
    p[0]=f2bf(w2.x);p[1]=f2bf(w2.y);p[2]=f2bf(w2.z);p[3]=f2bf(w2.w);
    p[4]=f2bf(w3.x);p[5]=f2bf(w3.y);p[6]=f2bf(w3.z);p[7]=f2bf(w3.w);
    *(bf16x8*)&Bs[sr * BK + (((sq * 2 + 1) ^ (sr & 7)) * 8)] = p;
    __syncthreads();

    #pragma unroll
    for (int kkb = 0; kkb < 2; ++kkb) {
      bf16x8 af[2], bw[2];
      const int q = kkb * 4 + (lane >> 4);
      #pragma unroll
      for (int i = 0; i < 2; ++i) {
        int ar = wm + i * 16 + (lane & 15);
        af[i] = *(const bf16x8*)&As[ar * BK + ((q ^ (ar & 7)) * 8)];
        int br = wn + i * 16 + (lane & 15);
        bw[i] = *(const bf16x8*)&Bs[br * BK + ((q ^ (br & 7)) * 8)];
      }
      #pragma unroll
      for (int i = 0; i < 2; ++i)
        #pragma unroll
        for (int j = 0; j < 2; ++j)
          acc[i][j] = __builtin_amdgcn_mfma_f32_16x16x32_bf16(af[i], bw[j], acc[i][j], 0, 0, 0);
    }
  }

  #pragma unroll
  for (int j = 0; j < 2; ++j) {
    int n = col0 + wn + j * 16 + (lane & 15);
    float bb = bv[n];
    #pragma unroll
    for (int i = 0; i < 2; ++i)
      #pragma unroll
      for (int r = 0; r < 4; ++r) {
        int m = row0 + wm + i * 16 + (lane >> 4) * 4 + r;
        outp[(size_t)m * HD + n] = fast_tanh(acc[i][j][r] + bb);
      }
  }
}

// ---- Stage 2: out[b,s,t,r] via MFMA; 8s x 16t tile, wave owns 2 s-rows.
//      LDS-staged (R11) + 1-deep ds_read->reg software pipeline: m+1's LDS
//      operands + Wout fragment load under m's pair_tanh chain. ----
__global__ __launch_bounds__(256, 5) void stage2_mfma(
    const float* __restrict__ ta, const float* __restrict__ tb,
    const short* __restrict__ Wob, float* __restrict__ out)
{
  constexpr int HC = 128, LDp = 132, NC = HD / HC;   // 6 chunks, 4 m-iters each
  const int b  = blockIdx.z;
  const int s0 = blockIdx.y * 8, t0 = blockIdx.x * 16;

  __shared__ float sa[8][LDp];
  __shared__ float sb[16][LDp];

  const int tid = threadIdx.x, wave = tid >> 6, lane = tid & 63;
  const int lg = lane >> 4;       // k sub-group (0..3) / output t-quad
  const int ln = lane & 15;       // A-row t / B-col r

  f32x4 acc[2] = {};

  const float* taB = ta + ((size_t)b * SQ + s0) * HD;
  const float* tbB = tb + ((size_t)b * SQ + t0) * HD;
  const short* wrow = Wob + (size_t)ln * HD + lg * 8;

  const int sr = tid >> 5, sq = tid & 31;

  // prologue: chunk 0 -> staging regs
  float4 va  = *(const float4*)(taB + (size_t)sr * HD + sq * 4);
  float4 vb0 = *(const float4*)(tbB + (size_t)sr * HD + sq * 4);
  float4 vb1 = *(const float4*)(tbB + (size_t)(sr + 8) * HD + sq * 4);

  const int r0 = wave * 2, r1 = wave * 2 + 1;

  for (int c = 0; c < NC; ++c) {
    *(float4*)&sa[sr][sq * 4]      = va;
    *(float4*)&sb[sr][sq * 4]      = vb0;
    *(float4*)&sb[sr + 8][sq * 4]  = vb1;
    __syncthreads();

    // next-chunk global staging (flies under this chunk's compute)
    if (c + 1 < NC) {
      va  = *(const float4*)(taB + (size_t)sr * HD + (c + 1) * HC + sq * 4);
      vb0 = *(const float4*)(tbB + (size_t)sr * HD + (c + 1) * HC + sq * 4);
      vb1 = *(const float4*)(tbB + (size_t)(sr + 8) * HD + (c + 1) * HC + sq * 4);
    }

    // preload m=0 operands into registers
    int kk0 = lg * 8;
    float4 cq0  = *(const float4*)&sb[ln][kk0];
    float4 cq1  = *(const float4*)&sb[ln][kk0 + 4];
    float4 ca00 = *(const float4*)&sa[r0][kk0];
    float4 ca01 = *(const float4*)&sa[r0][kk0 + 4];
    float4 ca10 = *(const float4*)&sa[r1][kk0];
    float4 ca11 = *(const float4*)&sa[r1][kk0 + 4];
    bf16x8 cbfr = *(const bf16x8*)(wrow + c * HC);

    #pragma unroll
    for (int m = 0; m < HC / 32; ++m) {
      float4 nq0, nq1, na00, na01, na10, na11;
      bf16x8 nbfr;
      if (m + 1 < HC / 32) {   // issue m+1's reads now; consumed next iter
        const int kk = (m + 1) * 32 + lg * 8;
        nq0  = *(const float4*)&sb[ln][kk];
        nq1  = *(const float4*)&sb[ln][kk + 4];
        na00 = *(const float4*)&sa[r0][kk];
        na01 = *(const float4*)&sa[r0][kk + 4];
        na10 = *(const float4*)&sa[r1][kk];
        na11 = *(const float4*)&sa[r1][kk + 4];
        nbfr = *(const bf16x8*)(wrow + c * HC + (m + 1) * 32);
      }

      f32x2 bv2[4] = {{cq0.x, cq0.y}, {cq0.z, cq0.w}, {cq1.x, cq1.y}, {cq1.z, cq1.w}};
      #pragma unroll
      for (int si = 0; si < 2; ++si) {
        float4 a0 = si ? ca10 : ca00;
        float4 a1 = si ? ca11 : ca01;
        f32x2 av2[4] = {{a0.x, a0.y}, {a0.z, a0.w}, {a1.x, a1.y}, {a1.z, a1.w}};
        bf16x8 pa;
        #pragma unroll
        for (int j = 0; j < 4; ++j) {
          // tanh(u+v) = (a+b)/(1+ab); packed f32 pairs
          f32x2 s = av2[j] + bv2[j];
          f32x2 d = av2[j] * bv2[j] + (f32x2){1.0f, 1.0f};
          f32x2 r;
          r[0] = __builtin_amdgcn_rcpf(d[0]);
          r[1] = __builtin_amdgcn_rcpf(d[1]);
          f32x2 res = s * r;
          pa[2 * j]     = f2bf(res[0]);
          pa[2 * j + 1] = f2bf(res[1]);
        }
        acc[si] = __builtin_amdgcn_mfma_f32_16x16x32_bf16(pa, cbfr, acc[si], 0, 0, 0);
      }

      if (m + 1 < HC / 32) {
        cq0 = nq0; cq1 = nq1;
        ca00 = na00; ca01 = na01; ca10 = na10; ca11 = na11;
        cbfr = nbfr;
      }
    }
    __syncthreads();
  }

  // D layout: row(M=t) = lg*4+reg, col(N=r) = ln
  if (ln < RR) {
    #pragma unroll
    for (int si = 0; si < 2; ++si) {
      int s = s0 + wave * 2 + si;
      float* op = out + (((size_t)b * SQ + s) * SQ + t0 + lg * 4) * RR + ln;
      op[0]      = acc[si][0];
      op[RR]     = acc[si][1];
      op[2 * RR] = acc[si][2];
      op[3 * RR] = acc[si][3];
    }
  }
}

extern "C" void kernel_launch(void* const* d_in, const int* in_sizes, int n_in,
                              void* d_out, int out_size, void* d_ws, size_t ws_size,
                              hipStream_t stream) {
  (void)in_sizes; (void)n_in; (void)out_size;
  const float* X    = (const float*)d_in[0];
  const float* Wsrc = (const float*)d_in[1];
  const float* bsrc = (const float*)d_in[2];
  const float* Wtgt = (const float*)d_in[3];
  const float* btgt = (const float*)d_in[4];
  const float* Wout = (const float*)d_in[5];
  float* out = (float*)d_out;

  float* taF = (float*)d_ws;                       // [1024,768] f32
  float* tbF = taF + (size_t)NB * SQ * HD;         // [1024,768] f32
  const size_t base = (size_t)2 * NB * SQ * HD * sizeof(float);
  short* Xb  = (short*)((char*)d_ws + base);
  short* Wsb = Xb + (size_t)NB * SQ * HD;
  short* Wtb = Wsb + (size_t)HD * HD;
  short* Wob = Wtb + (size_t)HD * HD;
  const size_t need = base +
      ((size_t)NB * SQ * HD + 2 * (size_t)HD * HD + (size_t)16 * HD) * sizeof(short);

  const short* WobUse;
  if (ws_size >= need) {
    const int total_oct = NB*SQ*HD/8 + 2*(HD*HD/8) + 16*HD/8;
    cvt_kernel<<<(total_oct + 255) / 256, 256, 0, stream>>>(
        X, Wsrc, Wtgt, Wout, Xb, Wsb, Wtb, Wob);
    stage1_lds<<<dim3(32, 12, 2), 256, 0, stream>>>(Xb, Wsb, bsrc, Wtb, btgt, taF, tbF);
    WobUse = Wob;
  } else {
    short* WobF = (short*)((char*)d_ws + base);
    cvt_wout<<<6, 256, 0, stream>>>(Wout, WobF);
    stage1_mfma<<<dim3(16, 12, 2), 256, 0, stream>>>(X, Wsrc, bsrc, Wtgt, btgt, taF, tbF);
    WobUse = WobF;
  }
  stage2_mfma<<<dim3(SQ / 16, SQ / 8, NB), 256, 0, stream>>>(taF, tbF, WobUse, out);
}